// Round 1
// 523.584 us; speedup vs baseline: 1.6943x; 1.6943x over previous
//
#include <hip/hip_runtime.h>
#include <cstddef>

#define HU    4096
#define NBLK  256
#define NTHR  512
#define MAXIT 100
#define TOL2  1e-7f

// workspace layout (float offsets) — WS_END = 30,313 floats = 121,252 B
#define WS_STS  0
#define WS_DINV 4096
#define WS_R0   8192
#define WS_U0   12288
#define WS_W    16384                    // DOUBLE buffer: 2 x 4096 (parity k&1)
#define WS_X    24576
#define WS_DEL  28672                    // (MAXIT+2)*16 slots
#define WS_BAR  (WS_DEL + (MAXIT + 2) * 16)   // 8 arrival counters
#define WS_FLAG (WS_BAR + 8)             // release flag (generation)
#define WS_END  (WS_FLAG + 1)

__device__ __forceinline__ float waveReduce(float v) {
#pragma unroll
  for (int off = 32; off > 0; off >>= 1) v += __shfl_xor(v, off, 64);
  return v;
}

// Block-wide sum over 8 waves; returns same value in all threads.
__device__ __forceinline__ float blockSum(float v, float* red) {
  v = waveReduce(v);
  if ((threadIdx.x & 63) == 0) red[threadIdx.x >> 6] = v;
  __syncthreads();
  float s = 0.f;
#pragma unroll
  for (int i = 0; i < 8; ++i) s += red[i];
  __syncthreads();
  return s;
}

// Master/release grid barrier: arrivals on 8 counters, block 0 polls the sum
// and publishes gen to flag; all others spin on the single flag word.
__device__ __forceinline__ void gsync(unsigned* cnt, unsigned* flag, unsigned gen) {
  __syncthreads();
  if (threadIdx.x == 0) {
    __threadfence();                     // release this block's global writes
    __hip_atomic_fetch_add(&cnt[blockIdx.x & 7], 1u,
                           __ATOMIC_RELEASE, __HIP_MEMORY_SCOPE_AGENT);
    if (blockIdx.x == 0) {
      const unsigned target = gen * NBLK;
      for (;;) {
        unsigned s = 0;
#pragma unroll
        for (int i = 0; i < 8; ++i)
          s += __hip_atomic_load(&cnt[i], __ATOMIC_RELAXED, __HIP_MEMORY_SCOPE_AGENT);
        if (s >= target) break;
        __builtin_amdgcn_s_sleep(1);
      }
      __hip_atomic_store(flag, gen, __ATOMIC_RELEASE, __HIP_MEMORY_SCOPE_AGENT);
    } else {
      while (__hip_atomic_load(flag, __ATOMIC_RELAXED, __HIP_MEMORY_SCOPE_AGENT) < gen)
        __builtin_amdgcn_s_sleep(1);
    }
    __threadfence();                     // acquire: invalidate stale cached lines
  }
  __syncthreads();
}

__global__ void __launch_bounds__(NTHR, 2)
cg_solve_kernel(const float* __restrict__ x_in, const float* __restrict__ L_in,
                const int* __restrict__ mask, const float* __restrict__ D,
                const float* __restrict__ thP, const float* __restrict__ S,
                const float* __restrict__ l1p, const float* __restrict__ l2p,
                const float* __restrict__ rhop, float* __restrict__ ws)
{
  __shared__ __align__(16) float r_l[HU];
  __shared__ __align__(16) float s_l[HU];
  __shared__ __align__(16) float u_l[HU];
  __shared__ __align__(16) float dinv_l[HU];
  __shared__ float red[8];
  unsigned* cnt  = (unsigned*)(ws + WS_BAR);
  unsigned* flag = (unsigned*)(ws + WS_FLAG);
  const float* sts = ws + WS_STS;
  const float lam1 = *l1p, lam2 = *l2p, rho = *rhop;
  const int tid = threadIdx.x, b = blockIdx.x;
  const int wv = tid >> 6, lane = tid & 63;
  unsigned gen = 0;

  // ---- init (blocks 0..7 write global sts/dinv/r0/u0) ----
  const int gtid = b * NTHR + tid;
  if (gtid < HU) {
    const int a = gtid >> 6, c = gtid & 63;
    float acc = 0.f, sdiag = 0.f;
    for (int h = 0; h < 64; ++h) {
      const float sa = S[h * 64 + a], sc = S[h * 64 + c];
      acc = fmaf(sa, sc, acc);
      sdiag = fmaf(sc, sc, sdiag);
    }
    ws[WS_STS + gtid] = acc;
    const float q = mask[gtid] ? 1.f : 0.f;
    const float diag = q + rho + lam1 * D[(size_t)gtid * (HU + 1)] + lam2 * sdiag;
    const float bb = rho * (L_in[gtid] - thP[gtid]) + (mask[gtid] ? x_in[gtid] : 0.f);
    const float di = 1.f / diag;
    ws[WS_DINV + gtid] = di;
    ws[WS_R0 + gtid] = bb;
    ws[WS_U0 + gtid] = bb * di;
  }
  gsync(cnt, flag, ++gen);

  // ---- every block mirrors r0,u0,dinv into its LDS; local gamma0 ----
  float acc0 = 0.f;
#pragma unroll
  for (int m = 0; m < 8; ++m) {
    const int i = tid + m * NTHR;
    const float rv = ws[WS_R0 + i], uv = ws[WS_U0 + i];
    r_l[i] = rv; u_l[i] = uv; dinv_l[i] = ws[WS_DINV + i];
    acc0 = fmaf(rv, uv, acc0);
  }
  const float gamma0 = blockSum(acc0, red);

  // redundant full x/p state: 8 elements per thread (static-indexed -> VGPRs)
  float p_arr[8], x_arr[8];
#pragma unroll
  for (int m = 0; m < 8; ++m) { p_arr[m] = 0.f; x_arr[m] = 0.f; }

  const int row0 = b * 16 + wv * 2;      // 2 rows per wave
  const int iq = row0 >> 6, j0 = row0 & 63;
  const float4* __restrict__ u4 = (const float4*)u_l;
  const float m0 = mask[row0] ? 1.f : 0.f;
  const float m1 = mask[row0 + 1] ? 1.f : 0.f;
  const float sts0 = sts[j0 * 64 + lane];
  const float sts1 = sts[j0 * 64 + 64 + lane];
  const float4* __restrict__ D0 = (const float4*)(D + (size_t)row0 * HU);
  const float4* __restrict__ D1 = D0 + 1024;

  float gamma = gamma0, gamma_prev = 1.f, alpha_prev = 1.f;
  for (int k = 0; k < MAXIT; ++k) {
    // ---- matvec: w = A u (u from LDS); delta partial (streaming loads) ----
    float* __restrict__ wbuf = ws + WS_W + (k & 1) * HU;
    {
      float acc_a = 0.f, acc_b = 0.f;
#pragma unroll
      for (int it = 0; it < 16; ++it) {
        const float4 uu = u4[it * 64 + lane];
        const float4 d0 = D0[it * 64 + lane];
        const float4 d1 = D1[it * 64 + lane];
        acc_a = fmaf(d0.x, uu.x, acc_a); acc_a = fmaf(d0.y, uu.y, acc_a);
        acc_a = fmaf(d0.z, uu.z, acc_a); acc_a = fmaf(d0.w, uu.w, acc_a);
        acc_b = fmaf(d1.x, uu.x, acc_b); acc_b = fmaf(d1.y, uu.y, acc_b);
        acc_b = fmaf(d1.z, uu.z, acc_b); acc_b = fmaf(d1.w, uu.w, acc_b);
      }
      const float us = u_l[iq * 64 + lane];
      float t0 = fmaf(lam1, acc_a, lam2 * (sts0 * us));
      float t1 = fmaf(lam1, acc_b, lam2 * (sts1 * us));
      t0 = waveReduce(t0);
      t1 = waveReduce(t1);
      const float u0v = u_l[row0], u1v = u_l[row0 + 1];
      const float w0 = t0 + (m0 + rho) * u0v;
      const float w1 = t1 + (m1 + rho) * u1v;
      if (lane == 0) {
        wbuf[row0] = w0;
        wbuf[row0 + 1] = w1;
        red[wv] = fmaf(w0, u0v, w1 * u1v);
      }
      __syncthreads();
      if (tid == 0) {
        float s = 0.f;
#pragma unroll
        for (int k2 = 0; k2 < 8; ++k2) s += red[k2];
        atomicAdd(&ws[WS_DEL + k * 16 + (b & 15)], s);
      }
    }
    gsync(cnt, flag, ++gen);             // the ONLY grid barrier per iteration

    // ---- scalars (identical in every block) ----
    float dk = 0.f;
#pragma unroll
    for (int i = 0; i < 16; ++i)
      dk += __hip_atomic_load(&ws[WS_DEL + k * 16 + i],
                              __ATOMIC_RELAXED, __HIP_MEMORY_SCOPE_AGENT);
    const float beta  = (k == 0) ? 0.f : gamma / gamma_prev;
    const float denom = (k == 0) ? dk  : (dk - beta * gamma / alpha_prev);
    const float alpha = gamma / denom;

    // ---- redundant local update (p/x use uold = u_k read BEFORE overwrite) ----
    float acc = 0.f;
#pragma unroll
    for (int m = 0; m < 8; ++m) {
      const int i = tid + m * NTHR;
      const float uold = u_l[i];                       // u_k
      const float wvv = wbuf[i];
      const float sv = (k == 0) ? wvv : fmaf(beta, s_l[i], wvv);
      s_l[i] = sv;
      const float rv = fmaf(-alpha, sv, r_l[i]);
      r_l[i] = rv;
      const float uv = rv * dinv_l[i];                 // u_{k+1}
      u_l[i] = uv;
      acc = fmaf(rv, uv, acc);
      const float pk = (k == 0) ? uold : fmaf(beta, p_arr[m], uold);
      p_arr[m] = pk;
      x_arr[m] = fmaf(alpha, pk, x_arr[m]);
    }
    const float gnext = blockSum(acc, red);  // also publishes u_l block-wide

    gamma_prev = gamma;
    alpha_prev = alpha;
    gamma = gnext;
    if (!(gnext > TOL2 * gamma0)) break; // uniform grid-wide (identical local math)
  }

  if (b == 0) {                          // all blocks hold identical x; block 0 writes
#pragma unroll
    for (int m = 0; m < 8; ++m) ws[WS_X + tid + m * NTHR] = x_arr[m];
  }
}

// ---------------------------------------------------------------------------
// SVT via ONE-SIDED Jacobi on Y = X + th_P (64x64).
// Same rotation trajectory as two-sided Jacobi on G = Y^T Y (the column dot
// products ARE the G entries), but each round only touches the 2 columns of
// each disjoint pair (b128 LDS ops) instead of full row+col passes over G,
// and needs ONE barrier per round instead of two.
// Final W columns = sigma_k * u_k, so Ltmp = W diag(relu(s-tau)/s) V^T
// directly — no G formation, no M = V f V^T, one final 64^3 matmul.
// ---------------------------------------------------------------------------

#define SWP 6          // max sweeps (matches baseline accuracy)
#define S_W 68         // column stride in floats (16B-aligned, bank-spreading)

// sum across each 16-lane group via DPP row_ror (VALU pipe, not LDS unit)
__device__ __forceinline__ float red16(float x) {
  int t;
  t = __builtin_amdgcn_update_dpp(0, __float_as_int(x), 0x128, 0xF, 0xF, false); // row_ror:8
  x += __int_as_float(t);
  t = __builtin_amdgcn_update_dpp(0, __float_as_int(x), 0x124, 0xF, 0xF, false); // row_ror:4
  x += __int_as_float(t);
  t = __builtin_amdgcn_update_dpp(0, __float_as_int(x), 0x122, 0xF, 0xF, false); // row_ror:2
  x += __int_as_float(t);
  t = __builtin_amdgcn_update_dpp(0, __float_as_int(x), 0x121, 0xF, 0xF, false); // row_ror:1
  x += __int_as_float(t);
  return x;
}

__global__ void __launch_bounds__(512)
svt_kernel(const float* __restrict__ thP, const float* __restrict__ vp,
           const float* __restrict__ cgp, const float* __restrict__ netap,
           const float* __restrict__ ws, float* __restrict__ out)
{
  const float* xsol = ws + WS_X;
  __shared__ __align__(16) float Wl[64 * S_W];   // W col-major: Wl[c*S_W + r]
  __shared__ __align__(16) float Vl[64 * S_W];   // V col-major
  __shared__ __align__(16) float Wt[64 * S_W];   // Wt[i*S_W+k] = W[k][i]*g[k]
  __shared__ float g_s[64];
  __shared__ float red[8];
  const int tid = threadIdx.x;

  // ---- load Y col-major, V = I; accumulate ||Y||_F^2 for exit threshold ----
  float t0acc = 0.f;
  for (int o = tid; o < 4096; o += 512) {
    const int r = o >> 6, c = o & 63;
    const float y = xsol[o] + thP[o];
    Wl[c * S_W + r] = y;
    Vl[c * S_W + r] = (r == c) ? 1.f : 0.f;
    t0acc = fmaf(y, y, t0acc);
  }
  const float T0 = blockSum(t0acc, red);     // also the init barrier
  const float thr = 1.6e-13f * T0 * T0;      // = 16 * 1e-14 * T0^2 (offacc is x16)

  // pair team: 16 threads per pair, 32 pairs; round-robin tournament schedule
  const int m = tid >> 4;                    // pair id 0..31
  const int sub = tid & 15;                  // slice within column (4 floats)
  int p = (m == 0) ? 63 : m;                 // p = (rnd+m)%63 (or fixed 63)
  int q = (m == 0) ? 0  : 63 - m;            // q = (rnd+63-m)%63

  for (int sweep = 0; sweep < SWP; ++sweep) {
    float offacc = 0.f;
    for (int rnd = 0; rnd < 63; ++rnd) {
      float4* wp = (float4*)(Wl + p * S_W) + sub;
      float4* wq = (float4*)(Wl + q * S_W) + sub;
      const float4 a = *wp, bb = *wq;
      float dpp = fmaf(a.x, a.x, fmaf(a.y, a.y, fmaf(a.z, a.z, a.w * a.w)));
      float dqq = fmaf(bb.x, bb.x, fmaf(bb.y, bb.y, fmaf(bb.z, bb.z, bb.w * bb.w)));
      float dpq = fmaf(a.x, bb.x, fmaf(a.y, bb.y, fmaf(a.z, bb.z, a.w * bb.w)));
      dpp = red16(dpp); dqq = red16(dqq); dpq = red16(dpq);
      offacc = fmaf(dpq, dpq, offacc);
      // Jacobi params (same formula as two-sided on G); branchless guard
      const float dsafe = (fabsf(dpq) < 1e-37f) ? 1e-37f : dpq;
      const float th = (dqq - dpp) / (2.f * dsafe);
      const float sg = (th >= 0.f) ? 1.f : -1.f;
      const float t  = sg / (fabsf(th) + sqrtf(fmaf(th, th, 1.f)));
      const float c1 = 1.f / sqrtf(fmaf(t, t, 1.f));
      const float s1 = t * c1;
      // rotate W columns
      float4 na, nb;
      na.x = c1 * a.x - s1 * bb.x;  nb.x = s1 * a.x + c1 * bb.x;
      na.y = c1 * a.y - s1 * bb.y;  nb.y = s1 * a.y + c1 * bb.y;
      na.z = c1 * a.z - s1 * bb.z;  nb.z = s1 * a.z + c1 * bb.z;
      na.w = c1 * a.w - s1 * bb.w;  nb.w = s1 * a.w + c1 * bb.w;
      *wp = na; *wq = nb;
      // rotate V columns (same J)
      float4* vp4 = (float4*)(Vl + p * S_W) + sub;
      float4* vq4 = (float4*)(Vl + q * S_W) + sub;
      const float4 va = *vp4, vb = *vq4;
      float4 nva, nvb;
      nva.x = c1 * va.x - s1 * vb.x;  nvb.x = s1 * va.x + c1 * vb.x;
      nva.y = c1 * va.y - s1 * vb.y;  nvb.y = s1 * va.y + c1 * vb.y;
      nva.z = c1 * va.z - s1 * vb.z;  nvb.z = s1 * va.z + c1 * vb.z;
      nva.w = c1 * va.w - s1 * vb.w;  nvb.w = s1 * va.w + c1 * vb.w;
      *vp4 = nva; *vq4 = nvb;
      // advance tournament (increment mod 63; m==0 keeps p=63)
      if (m) { p = (p + 1 == 63) ? 0 : p + 1; }
      q = (q + 1 == 63) ? 0 : q + 1;
      __syncthreads();                 // the ONLY barrier per round
    }
    // conservative early exit: only after >=4 sweeps, off-diag at rounding floor;
    // worst case identical to fixed 6 sweeps.
    const float tot = blockSum(offacc, red);
    if (sweep >= 3 && tot < thr) break;
  }

  // ---- singular values from column norms; soft-threshold gains ----
  if (tid < 64) {
    const float4* wc = (const float4*)(Wl + tid * S_W);
    float nn = 0.f;
#pragma unroll
    for (int i2 = 0; i2 < 16; ++i2) {
      const float4 u = wc[i2];
      nn = fmaf(u.x, u.x, fmaf(u.y, u.y, fmaf(u.z, u.z, fmaf(u.w, u.w, nn))));
    }
    const float sv = sqrtf(nn);
    const float tau = (*cgp) / (1.f + expf(-(*vp)));
    g_s[tid] = (sv > tau) ? (sv - tau) / sv : 0.f;   // relu(s-tau)/s
  }
  __syncthreads();

  // ---- Wt[i][k] = W[k][i] * g[k]  (row-major for broadcast+f4 matmul) ----
  for (int o = tid; o < 4096; o += 512) {
    const int i2 = o >> 6, k = o & 63;
    Wt[i2 * S_W + k] = Wl[k * S_W + i2] * g_s[k];
  }
  __syncthreads();

  // ---- Ltmp[i][j] = sum_k Wt[i][k] * V[k][j];  Ptmp = thP + neta (X - Ltmp) ----
  const float neta = *netap;
  const int j = tid & 63;
  const int ib = tid >> 6;
#pragma unroll
  for (int mm = 0; mm < 8; ++mm) {
    const int i2 = ib + 8 * mm;                       // uniform per wave
    const float4* wrow = (const float4*)(Wt + i2 * S_W);
    float acc = 0.f;
#pragma unroll
    for (int k4 = 0; k4 < 16; ++k4) {
      const float4 wv = wrow[k4];                     // LDS broadcast
      acc = fmaf(wv.x, Vl[(4 * k4 + 0) * S_W + j], acc);
      acc = fmaf(wv.y, Vl[(4 * k4 + 1) * S_W + j], acc);
      acc = fmaf(wv.z, Vl[(4 * k4 + 2) * S_W + j], acc);
      acc = fmaf(wv.w, Vl[(4 * k4 + 3) * S_W + j], acc);
    }
    const int o = i2 * 64 + j;
    out[o] = acc;                                     // Ltmp
    out[4096 + o] = thP[o] + neta * (xsol[o] - acc);  // Ptmp
  }
}

extern "C" void kernel_launch(void* const* d_in, const int* in_sizes, int n_in,
                              void* d_out, int out_size, void* d_ws, size_t ws_size,
                              hipStream_t stream)
{
  const float* x_in  = (const float*)d_in[0];
  const float* L_in  = (const float*)d_in[1];
  const int*   mask  = (const int*)d_in[2];
  const float* D     = (const float*)d_in[3];
  const float* thP   = (const float*)d_in[4];
  const float* vp    = (const float*)d_in[5];
  const float* cgp   = (const float*)d_in[6];
  const float* netap = (const float*)d_in[7];
  const float* l1p   = (const float*)d_in[8];
  const float* l2p   = (const float*)d_in[9];
  const float* rhop  = (const float*)d_in[10];
  const float* S     = (const float*)d_in[11];
  float* ws  = (float*)d_ws;
  float* out = (float*)d_out;

  // zero delta slots + barrier counters + flag (re-runs on every graph replay)
  hipMemsetAsync(ws + WS_DEL, 0, (WS_END - WS_DEL) * sizeof(float), stream);

  void* args[] = { (void*)&x_in, (void*)&L_in, (void*)&mask, (void*)&D, (void*)&thP,
                   (void*)&S, (void*)&l1p, (void*)&l2p, (void*)&rhop, (void*)&ws };
  hipLaunchCooperativeKernel((void*)cg_solve_kernel, dim3(NBLK), dim3(NTHR),
                             args, 0, stream);

  svt_kernel<<<1, 512, 0, stream>>>(thP, vp, cgp, netap, ws, out);
}

// Round 2
// 509.563 us; speedup vs baseline: 1.7409x; 1.0275x over previous
//
#include <hip/hip_runtime.h>
#include <cstddef>

#define HU    4096
#define NBLK  256
#define NTHR  512
#define MAXIT 100
#define TOL2  1e-7f

// workspace layout (float offsets) — WS_END = 30,313 floats = 121,252 B
#define WS_STS  0
#define WS_DINV 4096
#define WS_R0   8192
#define WS_U0   12288
#define WS_W    16384                    // DOUBLE buffer: 2 x 4096 (parity k&1)
#define WS_X    24576
#define WS_DEL  28672                    // (MAXIT+2)*16 slots
#define WS_BAR  (WS_DEL + (MAXIT + 2) * 16)   // 8 arrival counters
#define WS_FLAG (WS_BAR + 8)             // release flag (generation)
#define WS_END  (WS_FLAG + 1)

typedef _Float16 half4v __attribute__((ext_vector_type(4)));

__device__ __forceinline__ float waveReduce(float v) {
#pragma unroll
  for (int off = 32; off > 0; off >>= 1) v += __shfl_xor(v, off, 64);
  return v;
}

// Block-wide sum over 8 waves; returns same value in all threads.
__device__ __forceinline__ float blockSum(float v, float* red) {
  v = waveReduce(v);
  if ((threadIdx.x & 63) == 0) red[threadIdx.x >> 6] = v;
  __syncthreads();
  float s = 0.f;
#pragma unroll
  for (int i = 0; i < 8; ++i) s += red[i];
  __syncthreads();
  return s;
}

// Master/release grid barrier: arrivals on 8 counters, block 0 polls the sum
// and publishes gen to flag; all others spin on the single flag word.
__device__ __forceinline__ void gsync(unsigned* cnt, unsigned* flag, unsigned gen) {
  __syncthreads();
  if (threadIdx.x == 0) {
    __threadfence();                     // release this block's global writes
    __hip_atomic_fetch_add(&cnt[blockIdx.x & 7], 1u,
                           __ATOMIC_RELEASE, __HIP_MEMORY_SCOPE_AGENT);
    if (blockIdx.x == 0) {
      const unsigned target = gen * NBLK;
      for (;;) {
        unsigned s = 0;
#pragma unroll
        for (int i = 0; i < 8; ++i)
          s += __hip_atomic_load(&cnt[i], __ATOMIC_RELAXED, __HIP_MEMORY_SCOPE_AGENT);
        if (s >= target) break;
        __builtin_amdgcn_s_sleep(1);
      }
      __hip_atomic_store(flag, gen, __ATOMIC_RELEASE, __HIP_MEMORY_SCOPE_AGENT);
    } else {
      while (__hip_atomic_load(flag, __ATOMIC_RELAXED, __HIP_MEMORY_SCOPE_AGENT) < gen)
        __builtin_amdgcn_s_sleep(1);
    }
    __threadfence();                     // acquire: invalidate stale cached lines
  }
  __syncthreads();
}

__global__ void __launch_bounds__(NTHR, 1)
cg_solve_kernel(const float* __restrict__ x_in, const float* __restrict__ L_in,
                const int* __restrict__ mask, const float* __restrict__ D,
                const float* __restrict__ thP, const float* __restrict__ S,
                const float* __restrict__ l1p, const float* __restrict__ l2p,
                const float* __restrict__ rhop, float* __restrict__ ws)
{
  __shared__ __align__(16) float u_l[HU];          // 16 KB (block-shared u)
  __shared__ __align__(16) _Float16 Dh[16 * HU];   // 128 KB: this block's 16 D rows
  __shared__ float red[8];
  unsigned* cnt  = (unsigned*)(ws + WS_BAR);
  unsigned* flag = (unsigned*)(ws + WS_FLAG);
  const float* sts = ws + WS_STS;
  const float lam1 = *l1p, lam2 = *l2p, rho = *rhop;
  const int tid = threadIdx.x, b = blockIdx.x;
  const int wv = tid >> 6, lane = tid & 63;
  unsigned gen = 0;

  // ---- init (blocks 0..7 write global sts/dinv/r0/u0) ----
  const int gtid = b * NTHR + tid;
  if (gtid < HU) {
    const int a = gtid >> 6, c = gtid & 63;
    float acc = 0.f, sdiag = 0.f;
    for (int h = 0; h < 64; ++h) {
      const float sa = S[h * 64 + a], sc = S[h * 64 + c];
      acc = fmaf(sa, sc, acc);
      sdiag = fmaf(sc, sc, sdiag);
    }
    ws[WS_STS + gtid] = acc;
    const float q = mask[gtid] ? 1.f : 0.f;
    const float diag = q + rho + lam1 * D[(size_t)gtid * (HU + 1)] + lam2 * sdiag;
    const float bb = rho * (L_in[gtid] - thP[gtid]) + (mask[gtid] ? x_in[gtid] : 0.f);
    const float di = 1.f / diag;
    ws[WS_DINV + gtid] = di;
    ws[WS_R0 + gtid] = bb;
    ws[WS_U0 + gtid] = bb * di;
  }

  // ---- stage this block's 16 D rows into LDS as fp16 (one-time 64 MB read) ----
  {
    const float4* __restrict__ Dg = (const float4*)(D + (size_t)b * 16 * HU);
    half4v* __restrict__ Dh4 = (half4v*)Dh;
    for (int o = tid; o < 16 * HU / 4; o += NTHR) {
      const float4 dv = Dg[o];
      half4v h;
      h[0] = (_Float16)dv.x; h[1] = (_Float16)dv.y;
      h[2] = (_Float16)dv.z; h[3] = (_Float16)dv.w;
      Dh4[o] = h;
    }
  }
  gsync(cnt, flag, ++gen);

  // ---- every block mirrors r0,u0,dinv; r/s/dinv are thread-private -> regs ----
  float r_reg[8], s_reg[8], dinv_reg[8];
  float acc0 = 0.f;
#pragma unroll
  for (int m = 0; m < 8; ++m) {
    const int i = tid + m * NTHR;
    const float rv = ws[WS_R0 + i], uv = ws[WS_U0 + i];
    r_reg[m] = rv; u_l[i] = uv; dinv_reg[m] = ws[WS_DINV + i];
    s_reg[m] = 0.f;
  }
  __syncthreads();                       // u_l visible block-wide
#pragma unroll
  for (int m = 0; m < 8; ++m) acc0 = fmaf(r_reg[m], u_l[tid + m * NTHR], acc0);
  const float gamma0 = blockSum(acc0, red);

  // redundant full x/p state: 8 elements per thread (static-indexed -> VGPRs)
  float p_arr[8], x_arr[8];
#pragma unroll
  for (int m = 0; m < 8; ++m) { p_arr[m] = 0.f; x_arr[m] = 0.f; }

  const int row0 = b * 16 + wv * 2;      // 2 rows per wave
  const int iq = row0 >> 6, j0 = row0 & 63;
  const float4* __restrict__ u4 = (const float4*)u_l;
  const float m0 = mask[row0] ? 1.f : 0.f;
  const float m1 = mask[row0 + 1] ? 1.f : 0.f;
  const float sts0 = sts[j0 * 64 + lane];
  const float sts1 = sts[j0 * 64 + 64 + lane];
  // exact-diagonal correction: fp16(D_ii) error folded back in fp32
  const float dex0 = D[(size_t)row0 * (HU + 1)];
  const float dex1 = D[(size_t)(row0 + 1) * (HU + 1)];
  const float diagf0 = m0 + rho + lam1 * (dex0 - (float)(_Float16)dex0);
  const float diagf1 = m1 + rho + lam1 * (dex1 - (float)(_Float16)dex1);
  const half4v* __restrict__ H0 = (const half4v*)(Dh + (size_t)(wv * 2) * HU);
  const half4v* __restrict__ H1 = H0 + (HU / 4);

  float gamma = gamma0, gamma_prev = 1.f, alpha_prev = 1.f;
  for (int k = 0; k < MAXIT; ++k) {
    // ---- matvec: w = A u (u + fp16 D both from LDS) ----
    float* __restrict__ wbuf = ws + WS_W + (k & 1) * HU;
    {
      float acc_a = 0.f, acc_b = 0.f;
#pragma unroll
      for (int it = 0; it < 16; ++it) {
        const float4 uu = u4[it * 64 + lane];
        const half4v d0 = H0[it * 64 + lane];
        const half4v d1 = H1[it * 64 + lane];
        acc_a = fmaf((float)d0[0], uu.x, acc_a); acc_a = fmaf((float)d0[1], uu.y, acc_a);
        acc_a = fmaf((float)d0[2], uu.z, acc_a); acc_a = fmaf((float)d0[3], uu.w, acc_a);
        acc_b = fmaf((float)d1[0], uu.x, acc_b); acc_b = fmaf((float)d1[1], uu.y, acc_b);
        acc_b = fmaf((float)d1[2], uu.z, acc_b); acc_b = fmaf((float)d1[3], uu.w, acc_b);
      }
      const float us = u_l[iq * 64 + lane];
      float t0 = fmaf(lam1, acc_a, lam2 * (sts0 * us));
      float t1 = fmaf(lam1, acc_b, lam2 * (sts1 * us));
      t0 = waveReduce(t0);
      t1 = waveReduce(t1);
      const float u0v = u_l[row0], u1v = u_l[row0 + 1];
      const float w0 = t0 + diagf0 * u0v;
      const float w1 = t1 + diagf1 * u1v;
      if (lane == 0) {
        wbuf[row0] = w0;
        wbuf[row0 + 1] = w1;
        red[wv] = fmaf(w0, u0v, w1 * u1v);
      }
      __syncthreads();
      if (tid == 0) {
        float s = 0.f;
#pragma unroll
        for (int k2 = 0; k2 < 8; ++k2) s += red[k2];
        atomicAdd(&ws[WS_DEL + k * 16 + (b & 15)], s);
      }
    }
    gsync(cnt, flag, ++gen);             // the ONLY grid barrier per iteration

    // ---- scalars (identical in every block) ----
    float dk = 0.f;
#pragma unroll
    for (int i = 0; i < 16; ++i)
      dk += __hip_atomic_load(&ws[WS_DEL + k * 16 + i],
                              __ATOMIC_RELAXED, __HIP_MEMORY_SCOPE_AGENT);
    const float beta  = (k == 0) ? 0.f : gamma / gamma_prev;
    const float denom = (k == 0) ? dk  : (dk - beta * gamma / alpha_prev);
    const float alpha = gamma / denom;

    // ---- redundant local update (p/x use uold = u_k read BEFORE overwrite) ----
    float acc = 0.f;
#pragma unroll
    for (int m = 0; m < 8; ++m) {
      const int i = tid + m * NTHR;
      const float uold = u_l[i];                       // u_k
      const float wvv = wbuf[i];
      const float sv = (k == 0) ? wvv : fmaf(beta, s_reg[m], wvv);
      s_reg[m] = sv;
      const float rv = fmaf(-alpha, sv, r_reg[m]);
      r_reg[m] = rv;
      const float uv = rv * dinv_reg[m];               // u_{k+1}
      u_l[i] = uv;
      acc = fmaf(rv, uv, acc);
      const float pk = (k == 0) ? uold : fmaf(beta, p_arr[m], uold);
      p_arr[m] = pk;
      x_arr[m] = fmaf(alpha, pk, x_arr[m]);
    }
    const float gnext = blockSum(acc, red);  // barrier also publishes u_l

    gamma_prev = gamma;
    alpha_prev = alpha;
    gamma = gnext;
    if (!(gnext > TOL2 * gamma0)) break; // uniform grid-wide (identical local math)
  }

  if (b == 0) {                          // all blocks hold identical x; block 0 writes
#pragma unroll
    for (int m = 0; m < 8; ++m) ws[WS_X + tid + m * NTHR] = x_arr[m];
  }
}

// ---------------------------------------------------------------------------
// SVT via ONE-SIDED Jacobi on Y = X + th_P (64x64), V-LESS.
// W = Y V (V = product of rotations, never materialized). Since
// V^T = Sigma^-2 W^T Y, we get  Ltmp = W diag(g/sigma^2) W^T Y  with
// g = relu(sigma-tau)/sigma. Per round only the 2 W-columns of each pair are
// touched (4 b128 LDS ops/lane — half of the V-tracking version), one barrier.
// ---------------------------------------------------------------------------

#define SWP 6          // max sweeps
#define S_W 68         // column stride in floats (16B-aligned, bank-spreading)

// sum across each 16-lane group via DPP row_ror (VALU pipe, not LDS unit)
__device__ __forceinline__ float red16(float x) {
  int t;
  t = __builtin_amdgcn_update_dpp(0, __float_as_int(x), 0x128, 0xF, 0xF, false); // row_ror:8
  x += __int_as_float(t);
  t = __builtin_amdgcn_update_dpp(0, __float_as_int(x), 0x124, 0xF, 0xF, false); // row_ror:4
  x += __int_as_float(t);
  t = __builtin_amdgcn_update_dpp(0, __float_as_int(x), 0x122, 0xF, 0xF, false); // row_ror:2
  x += __int_as_float(t);
  t = __builtin_amdgcn_update_dpp(0, __float_as_int(x), 0x121, 0xF, 0xF, false); // row_ror:1
  x += __int_as_float(t);
  return x;
}

__global__ void __launch_bounds__(512)
svt_kernel(const float* __restrict__ thP, const float* __restrict__ vp,
           const float* __restrict__ cgp, const float* __restrict__ netap,
           const float* __restrict__ ws, float* __restrict__ out)
{
  const float* xsol = ws + WS_X;
  __shared__ __align__(16) float Wl[64 * S_W];   // W col-major: Wl[c*S_W + r]
  __shared__ __align__(16) float Yr[64 * S_W];   // pristine Y ROW-major
  __shared__ __align__(16) float T1[64 * S_W];   // T1[k][j] = (W^T Y)[k][j]
  __shared__ __align__(16) float Wr[64 * S_W];   // Wr[i][k] = W[i][k]*gg[k]
  __shared__ float g_s[64];
  __shared__ float red[8];
  const int tid = threadIdx.x;

  // ---- load Y (col-major working copy + row-major pristine); ||Y||_F^2 ----
  float t0acc = 0.f;
  for (int o = tid; o < 4096; o += 512) {
    const int r = o >> 6, c = o & 63;
    const float y = xsol[o] + thP[o];
    Wl[c * S_W + r] = y;
    Yr[r * S_W + c] = y;
    t0acc = fmaf(y, y, t0acc);
  }
  const float T0 = blockSum(t0acc, red);     // also the init barrier
  // exit when true off_F^2 <= 1e-11*T0^2 (offacc is x16: every lane counts)
  const float thr = 1.6e-10f * T0 * T0;

  // pair team: 16 threads per pair, 32 pairs; round-robin tournament schedule
  const int m = tid >> 4;                    // pair id 0..31
  const int sub = tid & 15;                  // slice within column (4 floats)
  int p = (m == 0) ? 63 : m;                 // p = (rnd+m)%63 (or fixed 63)
  int q = (m == 0) ? 0  : 63 - m;            // q = (rnd+63-m)%63

  for (int sweep = 0; sweep < SWP; ++sweep) {
    float offacc = 0.f;
    for (int rnd = 0; rnd < 63; ++rnd) {
      float4* wp = (float4*)(Wl + p * S_W) + sub;
      float4* wq = (float4*)(Wl + q * S_W) + sub;
      const float4 a = *wp, bb = *wq;
      float dpp = fmaf(a.x, a.x, fmaf(a.y, a.y, fmaf(a.z, a.z, a.w * a.w)));
      float dqq = fmaf(bb.x, bb.x, fmaf(bb.y, bb.y, fmaf(bb.z, bb.z, bb.w * bb.w)));
      float dpq = fmaf(a.x, bb.x, fmaf(a.y, bb.y, fmaf(a.z, bb.z, a.w * bb.w)));
      dpp = red16(dpp); dqq = red16(dqq); dpq = red16(dpq);
      offacc = fmaf(dpq, dpq, offacc);
      // Jacobi params; branchless guard
      const float dsafe = (fabsf(dpq) < 1e-37f) ? 1e-37f : dpq;
      const float th = (dqq - dpp) / (2.f * dsafe);
      const float sg = (th >= 0.f) ? 1.f : -1.f;
      const float t  = sg / (fabsf(th) + sqrtf(fmaf(th, th, 1.f)));
      const float c1 = 1.f / sqrtf(fmaf(t, t, 1.f));
      const float s1 = t * c1;
      // rotate W columns only (no V)
      float4 na, nb;
      na.x = c1 * a.x - s1 * bb.x;  nb.x = s1 * a.x + c1 * bb.x;
      na.y = c1 * a.y - s1 * bb.y;  nb.y = s1 * a.y + c1 * bb.y;
      na.z = c1 * a.z - s1 * bb.z;  nb.z = s1 * a.z + c1 * bb.z;
      na.w = c1 * a.w - s1 * bb.w;  nb.w = s1 * a.w + c1 * bb.w;
      *wp = na; *wq = nb;
      // advance tournament (increment mod 63; m==0 keeps p=63)
      if (m) { p = (p + 1 == 63) ? 0 : p + 1; }
      q = (q + 1 == 63) ? 0 : q + 1;
      __syncthreads();                 // the ONLY barrier per round
    }
    // early exit certifies the PRE-sweep state; post-sweep off is quadratically
    // smaller, so the 1/sigma^2 amplification below stays harmless.
    const float tot = blockSum(offacc, red);
    if (sweep >= 3 && tot < thr) break;
  }

  // ---- sigma from column norms; gg = relu(s-tau)/s^3 ----
  if (tid < 64) {
    const float4* wc = (const float4*)(Wl + tid * S_W);
    float nn = 0.f;
#pragma unroll
    for (int i2 = 0; i2 < 16; ++i2) {
      const float4 u = wc[i2];
      nn = fmaf(u.x, u.x, fmaf(u.y, u.y, fmaf(u.z, u.z, fmaf(u.w, u.w, nn))));
    }
    const float sv = sqrtf(nn);
    const float tau = (*cgp) / (1.f + expf(-(*vp)));
    g_s[tid] = (sv > tau) ? (sv - tau) / (sv * nn) : 0.f;   // (s-tau)/s^3
  }
  __syncthreads();

  const int j = tid & 63;
  const int ib = tid >> 6;

  // ---- T1[k][j] = sum_i W[i][k] * Y[i][j]   (W col broadcast, Y rows) ----
#pragma unroll
  for (int mm = 0; mm < 8; ++mm) {
    const int k = ib + 8 * mm;                        // uniform per wave
    const float4* wcol = (const float4*)(Wl + k * S_W);
    float acc = 0.f;
#pragma unroll
    for (int i4 = 0; i4 < 16; ++i4) {
      const float4 wv = wcol[i4];                     // LDS broadcast
      acc = fmaf(wv.x, Yr[(4 * i4 + 0) * S_W + j], acc);
      acc = fmaf(wv.y, Yr[(4 * i4 + 1) * S_W + j], acc);
      acc = fmaf(wv.z, Yr[(4 * i4 + 2) * S_W + j], acc);
      acc = fmaf(wv.w, Yr[(4 * i4 + 3) * S_W + j], acc);
    }
    T1[k * S_W + j] = acc;
  }
  // ---- Wr[i][k] = W[i][k] * gg[k] (transpose with gain fold) ----
  for (int o = tid; o < 4096; o += 512) {
    const int i2 = o >> 6, kk = o & 63;
    Wr[i2 * S_W + kk] = Wl[kk * S_W + i2] * g_s[kk];
  }
  __syncthreads();

  // ---- Ltmp[i][j] = sum_k Wr[i][k] * T1[k][j]; Ptmp = thP + neta (X - Ltmp) ----
  const float neta = *netap;
#pragma unroll
  for (int mm = 0; mm < 8; ++mm) {
    const int i2 = ib + 8 * mm;                       // uniform per wave
    const float4* wrow = (const float4*)(Wr + i2 * S_W);
    float acc = 0.f;
#pragma unroll
    for (int k4 = 0; k4 < 16; ++k4) {
      const float4 wv = wrow[k4];                     // LDS broadcast
      acc = fmaf(wv.x, T1[(4 * k4 + 0) * S_W + j], acc);
      acc = fmaf(wv.y, T1[(4 * k4 + 1) * S_W + j], acc);
      acc = fmaf(wv.z, T1[(4 * k4 + 2) * S_W + j], acc);
      acc = fmaf(wv.w, T1[(4 * k4 + 3) * S_W + j], acc);
    }
    const int o = i2 * 64 + j;
    out[o] = acc;                                     // Ltmp
    out[4096 + o] = thP[o] + neta * (xsol[o] - acc);  // Ptmp
  }
}

extern "C" void kernel_launch(void* const* d_in, const int* in_sizes, int n_in,
                              void* d_out, int out_size, void* d_ws, size_t ws_size,
                              hipStream_t stream)
{
  const float* x_in  = (const float*)d_in[0];
  const float* L_in  = (const float*)d_in[1];
  const int*   mask  = (const int*)d_in[2];
  const float* D     = (const float*)d_in[3];
  const float* thP   = (const float*)d_in[4];
  const float* vp    = (const float*)d_in[5];
  const float* cgp   = (const float*)d_in[6];
  const float* netap = (const float*)d_in[7];
  const float* l1p   = (const float*)d_in[8];
  const float* l2p   = (const float*)d_in[9];
  const float* rhop  = (const float*)d_in[10];
  const float* S     = (const float*)d_in[11];
  float* ws  = (float*)d_ws;
  float* out = (float*)d_out;

  // zero delta slots + barrier counters + flag (re-runs on every graph replay)
  hipMemsetAsync(ws + WS_DEL, 0, (WS_END - WS_DEL) * sizeof(float), stream);

  void* args[] = { (void*)&x_in, (void*)&L_in, (void*)&mask, (void*)&D, (void*)&thP,
                   (void*)&S, (void*)&l1p, (void*)&l2p, (void*)&rhop, (void*)&ws };
  hipLaunchCooperativeKernel((void*)cg_solve_kernel, dim3(NBLK), dim3(NTHR),
                             args, 0, stream);

  svt_kernel<<<1, 512, 0, stream>>>(thP, vp, cgp, netap, ws, out);
}

// Round 3
// 351.554 us; speedup vs baseline: 2.5234x; 1.4495x over previous
//
#include <hip/hip_runtime.h>
#include <cstddef>

#define HU    4096
#define NBLK  256
#define NTHR  512
#define MAXIT 100
#define TOL2  1e-7f

// workspace layout (float offsets)
#define WS_STS  0
#define WS_DINV 4096
#define WS_R0   8192
#define WS_U0   12288
#define WS_W    16384                    // DOUBLE buffer: 2 x 4096 (parity k&1)
#define WS_X    24576
#define WS_DEL  28672                    // (MAXIT+2)*64 slots (k-indexed, 4 lines wide)
#define WS_BAR  (WS_DEL + (MAXIT + 2) * 64)   // 8 arrival counters, 64B-strided
#define WS_FLAG (WS_BAR + 8 * 16)        // release flag (generation)
#define WS_END  (WS_FLAG + 1)

typedef _Float16 half4v __attribute__((ext_vector_type(4)));

// raw-approx transcendentals (1 ulp-ish) — avoids hipcc's IEEE div/sqrt
// expansion (~45 instrs, ~150cy serial chain) on the Jacobi critical path.
__device__ __forceinline__ float fastrcp(float x) {
  float r; asm("v_rcp_f32 %0, %1" : "=v"(r) : "v"(x)); return r;
}
__device__ __forceinline__ float fastsqrt(float x) {
  float r; asm("v_sqrt_f32 %0, %1" : "=v"(r) : "v"(x)); return r;
}
__device__ __forceinline__ float fastrsq(float x) {
  float r; asm("v_rsq_f32 %0, %1" : "=v"(r) : "v"(x)); return r;
}

__device__ __forceinline__ float waveReduce(float v) {
#pragma unroll
  for (int off = 32; off > 0; off >>= 1) v += __shfl_xor(v, off, 64);
  return v;
}

// Block-wide sum over 8 waves; returns same value in all threads.
__device__ __forceinline__ float blockSum(float v, float* red) {
  v = waveReduce(v);
  if ((threadIdx.x & 63) == 0) red[threadIdx.x >> 6] = v;
  __syncthreads();
  float s = 0.f;
#pragma unroll
  for (int i = 0; i < 8; ++i) s += red[i];
  __syncthreads();
  return s;
}

// Master/release grid barrier: arrivals on 8 cache-line-separated counters,
// block 0 polls the sum and publishes gen to flag; others spin on the flag.
__device__ __forceinline__ void gsync(unsigned* cnt, unsigned* flag, unsigned gen) {
  __syncthreads();
  if (threadIdx.x == 0) {
    __threadfence();                     // release this block's global writes
    __hip_atomic_fetch_add(&cnt[(blockIdx.x & 7) * 16], 1u,
                           __ATOMIC_RELEASE, __HIP_MEMORY_SCOPE_AGENT);
    if (blockIdx.x == 0) {
      const unsigned target = gen * NBLK;
      for (;;) {
        unsigned s = 0;
#pragma unroll
        for (int i = 0; i < 8; ++i)
          s += __hip_atomic_load(&cnt[i * 16], __ATOMIC_RELAXED, __HIP_MEMORY_SCOPE_AGENT);
        if (s >= target) break;
        __builtin_amdgcn_s_sleep(1);
      }
      __hip_atomic_store(flag, gen, __ATOMIC_RELEASE, __HIP_MEMORY_SCOPE_AGENT);
    } else {
      while (__hip_atomic_load(flag, __ATOMIC_RELAXED, __HIP_MEMORY_SCOPE_AGENT) < gen)
        __builtin_amdgcn_s_sleep(1);
    }
    __threadfence();                     // acquire: invalidate stale cached lines
  }
  __syncthreads();
}

__global__ void __launch_bounds__(NTHR, 1)
cg_solve_kernel(const float* __restrict__ x_in, const float* __restrict__ L_in,
                const int* __restrict__ mask, const float* __restrict__ D,
                const float* __restrict__ thP, const float* __restrict__ S,
                const float* __restrict__ l1p, const float* __restrict__ l2p,
                const float* __restrict__ rhop, float* __restrict__ ws)
{
  __shared__ __align__(16) float u_l[HU];          // 16 KB (block-shared u)
  __shared__ __align__(16) _Float16 Dh[16 * HU];   // 128 KB: this block's 16 D rows
  __shared__ float red[8];
  unsigned* cnt  = (unsigned*)(ws + WS_BAR);
  unsigned* flag = (unsigned*)(ws + WS_FLAG);
  const float* sts = ws + WS_STS;
  const float lam1 = *l1p, lam2 = *l2p, rho = *rhop;
  const int tid = threadIdx.x, b = blockIdx.x;
  const int wv = tid >> 6, lane = tid & 63;
  unsigned gen = 0;

  // ---- init (blocks 0..7 write global sts/dinv/r0/u0) ----
  const int gtid = b * NTHR + tid;
  if (gtid < HU) {
    const int a = gtid >> 6, c = gtid & 63;
    float acc = 0.f, sdiag = 0.f;
    for (int h = 0; h < 64; ++h) {
      const float sa = S[h * 64 + a], sc = S[h * 64 + c];
      acc = fmaf(sa, sc, acc);
      sdiag = fmaf(sc, sc, sdiag);
    }
    ws[WS_STS + gtid] = acc;
    const float q = mask[gtid] ? 1.f : 0.f;
    const float diag = q + rho + lam1 * D[(size_t)gtid * (HU + 1)] + lam2 * sdiag;
    const float bb = rho * (L_in[gtid] - thP[gtid]) + (mask[gtid] ? x_in[gtid] : 0.f);
    const float di = 1.f / diag;
    ws[WS_DINV + gtid] = di;
    ws[WS_R0 + gtid] = bb;
    ws[WS_U0 + gtid] = bb * di;
  }

  // ---- stage this block's 16 D rows into LDS as fp16 (one-time 64 MB read) ----
  {
    const float4* __restrict__ Dg = (const float4*)(D + (size_t)b * 16 * HU);
    half4v* __restrict__ Dh4 = (half4v*)Dh;
    for (int o = tid; o < 16 * HU / 4; o += NTHR) {
      const float4 dv = Dg[o];
      half4v h;
      h[0] = (_Float16)dv.x; h[1] = (_Float16)dv.y;
      h[2] = (_Float16)dv.z; h[3] = (_Float16)dv.w;
      Dh4[o] = h;
    }
  }
  gsync(cnt, flag, ++gen);

  // ---- every block mirrors r0,u0,dinv; r/s/dinv are thread-private -> regs ----
  float r_reg[8], s_reg[8], dinv_reg[8];
  float acc0 = 0.f;
#pragma unroll
  for (int m = 0; m < 8; ++m) {
    const int i = tid + m * NTHR;
    const float rv = ws[WS_R0 + i], uv = ws[WS_U0 + i];
    r_reg[m] = rv; u_l[i] = uv; dinv_reg[m] = ws[WS_DINV + i];
    s_reg[m] = 0.f;
  }
  __syncthreads();                       // u_l visible block-wide
#pragma unroll
  for (int m = 0; m < 8; ++m) acc0 = fmaf(r_reg[m], u_l[tid + m * NTHR], acc0);
  const float gamma0 = blockSum(acc0, red);

  // redundant full x/p state: 8 elements per thread (static-indexed -> VGPRs)
  float p_arr[8], x_arr[8];
#pragma unroll
  for (int m = 0; m < 8; ++m) { p_arr[m] = 0.f; x_arr[m] = 0.f; }

  const int row0 = b * 16 + wv * 2;      // 2 rows per wave
  const int iq = row0 >> 6, j0 = row0 & 63;
  const float4* __restrict__ u4 = (const float4*)u_l;
  const float m0 = mask[row0] ? 1.f : 0.f;
  const float m1 = mask[row0 + 1] ? 1.f : 0.f;
  const float sts0 = sts[j0 * 64 + lane];
  const float sts1 = sts[j0 * 64 + 64 + lane];
  // exact-diagonal correction: fp16(D_ii) error folded back in fp32
  const float dex0 = D[(size_t)row0 * (HU + 1)];
  const float dex1 = D[(size_t)(row0 + 1) * (HU + 1)];
  const float diagf0 = m0 + rho + lam1 * (dex0 - (float)(_Float16)dex0);
  const float diagf1 = m1 + rho + lam1 * (dex1 - (float)(_Float16)dex1);
  const half4v* __restrict__ H0 = (const half4v*)(Dh + (size_t)(wv * 2) * HU);
  const half4v* __restrict__ H1 = H0 + (HU / 4);

  float gamma = gamma0, gamma_prev = 1.f, alpha_prev = 1.f;
  for (int k = 0; k < MAXIT; ++k) {
    // ---- matvec: w = A u (u + fp16 D both from LDS) ----
    float* __restrict__ wbuf = ws + WS_W + (k & 1) * HU;
    {
      float acc_a = 0.f, acc_b = 0.f;
#pragma unroll
      for (int it = 0; it < 16; ++it) {
        const float4 uu = u4[it * 64 + lane];
        const half4v d0 = H0[it * 64 + lane];
        const half4v d1 = H1[it * 64 + lane];
        acc_a = fmaf((float)d0[0], uu.x, acc_a); acc_a = fmaf((float)d0[1], uu.y, acc_a);
        acc_a = fmaf((float)d0[2], uu.z, acc_a); acc_a = fmaf((float)d0[3], uu.w, acc_a);
        acc_b = fmaf((float)d1[0], uu.x, acc_b); acc_b = fmaf((float)d1[1], uu.y, acc_b);
        acc_b = fmaf((float)d1[2], uu.z, acc_b); acc_b = fmaf((float)d1[3], uu.w, acc_b);
      }
      const float us = u_l[iq * 64 + lane];
      float t0 = fmaf(lam1, acc_a, lam2 * (sts0 * us));
      float t1 = fmaf(lam1, acc_b, lam2 * (sts1 * us));
      t0 = waveReduce(t0);
      t1 = waveReduce(t1);
      const float u0v = u_l[row0], u1v = u_l[row0 + 1];
      const float w0 = t0 + diagf0 * u0v;
      const float w1 = t1 + diagf1 * u1v;
      if (lane == 0) {
        wbuf[row0] = w0;
        wbuf[row0 + 1] = w1;
        red[wv] = fmaf(w0, u0v, w1 * u1v);
      }
      __syncthreads();
      if (tid == 0) {
        float s = 0.f;
#pragma unroll
        for (int k2 = 0; k2 < 8; ++k2) s += red[k2];
        atomicAdd(&ws[WS_DEL + k * 64 + (b & 63)], s);
      }
    }
    gsync(cnt, flag, ++gen);             // the ONLY grid barrier per iteration

    // ---- scalars (identical in every block/wave: same loads, same order) ----
    const float dk = waveReduce(ws[WS_DEL + k * 64 + lane]);
    const float beta  = (k == 0) ? 0.f : gamma * fastrcp(gamma_prev);
    const float denom = (k == 0) ? dk  : (dk - beta * gamma * fastrcp(alpha_prev));
    const float alpha = gamma * fastrcp(denom);

    // ---- redundant local update (p/x use uold = u_k read BEFORE overwrite) ----
    float acc = 0.f;
#pragma unroll
    for (int m = 0; m < 8; ++m) {
      const int i = tid + m * NTHR;
      const float uold = u_l[i];                       // u_k
      const float wvv = wbuf[i];
      const float sv = (k == 0) ? wvv : fmaf(beta, s_reg[m], wvv);
      s_reg[m] = sv;
      const float rv = fmaf(-alpha, sv, r_reg[m]);
      r_reg[m] = rv;
      const float uv = rv * dinv_reg[m];               // u_{k+1}
      u_l[i] = uv;
      acc = fmaf(rv, uv, acc);
      const float pk = (k == 0) ? uold : fmaf(beta, p_arr[m], uold);
      p_arr[m] = pk;
      x_arr[m] = fmaf(alpha, pk, x_arr[m]);
    }
    const float gnext = blockSum(acc, red);  // barrier also publishes u_l

    gamma_prev = gamma;
    alpha_prev = alpha;
    gamma = gnext;
    if (!(gnext > TOL2 * gamma0)) break; // uniform grid-wide (identical local math)
  }

  if (b == 0) {                          // all blocks hold identical x; block 0 writes
#pragma unroll
    for (int m = 0; m < 8; ++m) ws[WS_X + tid + m * NTHR] = x_arr[m];
  }
}

// ---------------------------------------------------------------------------
// SVT via ONE-SIDED Jacobi on Y = X + th_P (64x64), V-LESS.
// W = Y V (V never materialized). V^T = Sigma^-2 W^T Y, so
// Ltmp = W diag(g/sigma^2) W^T Y with g = relu(sigma-tau)/sigma.
// Per round: 2 b128 reads + (usually) 2 b128 writes per lane, one barrier.
// Jacobi params use raw v_rcp/v_sqrt/v_rsq (c^2+s^2 = 1 +- 3e-7: cumulative
// column-norm drift ~1e-4 over 378 rotations — far below tolerance).
// Converged pairs (dpq^2 <= 1e-14 dpp dqq) skip the rotation entirely
// (team-uniform branch); their off^2 still feeds the exit certificate.
// ---------------------------------------------------------------------------

#define SWP 6          // max sweeps
#define S_W 68         // column stride in floats (16B-aligned, bank-spreading)

// sum across each 16-lane group via DPP row_ror (VALU pipe, not LDS unit)
__device__ __forceinline__ float red16(float x) {
  int t;
  t = __builtin_amdgcn_update_dpp(0, __float_as_int(x), 0x128, 0xF, 0xF, false); // row_ror:8
  x += __int_as_float(t);
  t = __builtin_amdgcn_update_dpp(0, __float_as_int(x), 0x124, 0xF, 0xF, false); // row_ror:4
  x += __int_as_float(t);
  t = __builtin_amdgcn_update_dpp(0, __float_as_int(x), 0x122, 0xF, 0xF, false); // row_ror:2
  x += __int_as_float(t);
  t = __builtin_amdgcn_update_dpp(0, __float_as_int(x), 0x121, 0xF, 0xF, false); // row_ror:1
  x += __int_as_float(t);
  return x;
}

__global__ void __launch_bounds__(512)
svt_kernel(const float* __restrict__ thP, const float* __restrict__ vp,
           const float* __restrict__ cgp, const float* __restrict__ netap,
           const float* __restrict__ ws, float* __restrict__ out)
{
  const float* xsol = ws + WS_X;
  __shared__ __align__(16) float Wl[64 * S_W];   // W col-major: Wl[c*S_W + r]
  __shared__ __align__(16) float Yr[64 * S_W];   // pristine Y ROW-major
  __shared__ __align__(16) float T1[64 * S_W];   // T1[k][j] = (W^T Y)[k][j]
  __shared__ __align__(16) float Wr[64 * S_W];   // Wr[i][k] = W[i][k]*gg[k]
  __shared__ float g_s[64];
  __shared__ float red[8];
  const int tid = threadIdx.x;

  // ---- load Y (col-major working copy + row-major pristine); ||Y||_F^2 ----
  float t0acc = 0.f;
  for (int o = tid; o < 4096; o += 512) {
    const int r = o >> 6, c = o & 63;
    const float y = xsol[o] + thP[o];
    Wl[c * S_W + r] = y;
    Yr[r * S_W + c] = y;
    t0acc = fmaf(y, y, t0acc);
  }
  const float T0 = blockSum(t0acc, red);     // also the init barrier
  // exit when true off_F^2 <= 1e-11*T0^2 (offacc is x16: every lane counts)
  const float thr = 1.6e-10f * T0 * T0;

  // pair team: 16 threads per pair, 32 pairs; round-robin tournament schedule
  const int m = tid >> 4;                    // pair id 0..31
  const int sub = tid & 15;                  // slice within column (4 floats)
  int p = (m == 0) ? 63 : m;                 // p = (rnd+m)%63 (or fixed 63)
  int q = (m == 0) ? 0  : 63 - m;            // q = (rnd+63-m)%63

  for (int sweep = 0; sweep < SWP; ++sweep) {
    float offacc = 0.f;
    for (int rnd = 0; rnd < 63; ++rnd) {
      float4* wp = (float4*)(Wl + p * S_W) + sub;
      float4* wq = (float4*)(Wl + q * S_W) + sub;
      const float4 a = *wp, bb = *wq;
      float dpp = fmaf(a.x, a.x, fmaf(a.y, a.y, fmaf(a.z, a.z, a.w * a.w)));
      float dqq = fmaf(bb.x, bb.x, fmaf(bb.y, bb.y, fmaf(bb.z, bb.z, bb.w * bb.w)));
      float dpq = fmaf(a.x, bb.x, fmaf(a.y, bb.y, fmaf(a.z, bb.z, a.w * bb.w)));
      dpp = red16(dpp); dqq = red16(dqq); dpq = red16(dpq);
      offacc = fmaf(dpq, dpq, offacc);
      // team-uniform skip of converged pairs (dpq/dpp/dqq identical in team)
      if (dpq * dpq > 1e-14f * dpp * dqq) {
        const float th = (dqq - dpp) * 0.5f * fastrcp(dpq);
        const float sg = (th >= 0.f) ? 1.f : -1.f;
        const float t  = sg * fastrcp(fabsf(th) + fastsqrt(fmaf(th, th, 1.f)));
        const float c1 = fastrsq(fmaf(t, t, 1.f));
        const float s1 = t * c1;
        float4 na, nb;
        na.x = c1 * a.x - s1 * bb.x;  nb.x = s1 * a.x + c1 * bb.x;
        na.y = c1 * a.y - s1 * bb.y;  nb.y = s1 * a.y + c1 * bb.y;
        na.z = c1 * a.z - s1 * bb.z;  nb.z = s1 * a.z + c1 * bb.z;
        na.w = c1 * a.w - s1 * bb.w;  nb.w = s1 * a.w + c1 * bb.w;
        *wp = na; *wq = nb;
      }
      // advance tournament (increment mod 63; m==0 keeps p=63)
      if (m) { p = (p + 1 == 63) ? 0 : p + 1; }
      q = (q + 1 == 63) ? 0 : q + 1;
      __syncthreads();                 // the ONLY barrier per round
    }
    // early exit certifies the PRE-sweep state; post-sweep off is quadratically
    // smaller, so the 1/sigma^2 amplification below stays harmless.
    const float tot = blockSum(offacc, red);
    if (sweep >= 3 && tot < thr) break;
  }

  // ---- sigma from column norms; gg = relu(s-tau)/s^3 ----
  if (tid < 64) {
    const float4* wc = (const float4*)(Wl + tid * S_W);
    float nn = 0.f;
#pragma unroll
    for (int i2 = 0; i2 < 16; ++i2) {
      const float4 u = wc[i2];
      nn = fmaf(u.x, u.x, fmaf(u.y, u.y, fmaf(u.z, u.z, fmaf(u.w, u.w, nn))));
    }
    const float sv = sqrtf(nn);
    const float tau = (*cgp) / (1.f + expf(-(*vp)));
    g_s[tid] = (sv > tau) ? (sv - tau) / (sv * nn) : 0.f;   // (s-tau)/s^3
  }
  __syncthreads();

  const int j = tid & 63;
  const int ib = tid >> 6;

  // ---- T1[k][j] = sum_i W[i][k] * Y[i][j]   (W col broadcast, Y rows) ----
#pragma unroll
  for (int mm = 0; mm < 8; ++mm) {
    const int k = ib + 8 * mm;                        // uniform per wave
    const float4* wcol = (const float4*)(Wl + k * S_W);
    float acc = 0.f;
#pragma unroll
    for (int i4 = 0; i4 < 16; ++i4) {
      const float4 wv = wcol[i4];                     // LDS broadcast
      acc = fmaf(wv.x, Yr[(4 * i4 + 0) * S_W + j], acc);
      acc = fmaf(wv.y, Yr[(4 * i4 + 1) * S_W + j], acc);
      acc = fmaf(wv.z, Yr[(4 * i4 + 2) * S_W + j], acc);
      acc = fmaf(wv.w, Yr[(4 * i4 + 3) * S_W + j], acc);
    }
    T1[k * S_W + j] = acc;
  }
  // ---- Wr[i][k] = W[i][k] * gg[k] (transpose with gain fold) ----
  for (int o = tid; o < 4096; o += 512) {
    const int i2 = o >> 6, kk = o & 63;
    Wr[i2 * S_W + kk] = Wl[kk * S_W + i2] * g_s[kk];
  }
  __syncthreads();

  // ---- Ltmp[i][j] = sum_k Wr[i][k] * T1[k][j]; Ptmp = thP + neta (X - Ltmp) ----
  const float neta = *netap;
#pragma unroll
  for (int mm = 0; mm < 8; ++mm) {
    const int i2 = ib + 8 * mm;                       // uniform per wave
    const float4* wrow = (const float4*)(Wr + i2 * S_W);
    float acc = 0.f;
#pragma unroll
    for (int k4 = 0; k4 < 16; ++k4) {
      const float4 wv = wrow[k4];                     // LDS broadcast
      acc = fmaf(wv.x, T1[(4 * k4 + 0) * S_W + j], acc);
      acc = fmaf(wv.y, T1[(4 * k4 + 1) * S_W + j], acc);
      acc = fmaf(wv.z, T1[(4 * k4 + 2) * S_W + j], acc);
      acc = fmaf(wv.w, T1[(4 * k4 + 3) * S_W + j], acc);
    }
    const int o = i2 * 64 + j;
    out[o] = acc;                                     // Ltmp
    out[4096 + o] = thP[o] + neta * (xsol[o] - acc);  // Ptmp
  }
}

extern "C" void kernel_launch(void* const* d_in, const int* in_sizes, int n_in,
                              void* d_out, int out_size, void* d_ws, size_t ws_size,
                              hipStream_t stream)
{
  const float* x_in  = (const float*)d_in[0];
  const float* L_in  = (const float*)d_in[1];
  const int*   mask  = (const int*)d_in[2];
  const float* D     = (const float*)d_in[3];
  const float* thP   = (const float*)d_in[4];
  const float* vp    = (const float*)d_in[5];
  const float* cgp   = (const float*)d_in[6];
  const float* netap = (const float*)d_in[7];
  const float* l1p   = (const float*)d_in[8];
  const float* l2p   = (const float*)d_in[9];
  const float* rhop  = (const float*)d_in[10];
  const float* S     = (const float*)d_in[11];
  float* ws  = (float*)d_ws;
  float* out = (float*)d_out;

  // zero delta slots + barrier counters + flag (re-runs on every graph replay)
  hipMemsetAsync(ws + WS_DEL, 0, (WS_END - WS_DEL) * sizeof(float), stream);

  void* args[] = { (void*)&x_in, (void*)&L_in, (void*)&mask, (void*)&D, (void*)&thP,
                   (void*)&S, (void*)&l1p, (void*)&l2p, (void*)&rhop, (void*)&ws };
  hipLaunchCooperativeKernel((void*)cg_solve_kernel, dim3(NBLK), dim3(NTHR),
                             args, 0, stream);

  svt_kernel<<<1, 512, 0, stream>>>(thP, vp, cgp, netap, ws, out);
}